// Round 15
// baseline (980.384 us; speedup 1.0000x reference)
//
#include <hip/hip_runtime.h>
#include <stdint.h>

// ---------------- common types / helpers ----------------
typedef unsigned short u16;
typedef short s16x8 __attribute__((ext_vector_type(8)));
typedef unsigned short u16x4 __attribute__((ext_vector_type(4)));
typedef float f32x4 __attribute__((ext_vector_type(4)));

#define DEV static __device__ __forceinline__

DEV u16 f2b(float f) {
  union { float f; unsigned u; } v; v.f = f;
  unsigned r = v.u + 0x7fffu + ((v.u >> 16) & 1u);
  return (u16)(r >> 16);
}
DEV float b2f(u16 b) {
  union { unsigned u; float f; } v; v.u = ((unsigned)b) << 16; return v.f;
}
// pack bf16(trunc(a)), bf16(trunc(b)) into one u32 with a single v_perm_b32
DEV unsigned pk_trunc(float a, float b) {
  return __builtin_amdgcn_perm(__float_as_uint(b), __float_as_uint(a), 0x07060302u);
}
DEV f32x4 MFMA16(s16x8 a, s16x8 b, f32x4 c) {
  return __builtin_amdgcn_mfma_f32_16x16x32_bf16(a, b, c, 0, 0, 0);
}
#define GLD_LDS16(gp, lp)                                                            \
  __builtin_amdgcn_global_load_lds((const __attribute__((address_space(1))) void*)(gp), \
                                   (__attribute__((address_space(3))) void*)(lp), 16, 0, 0)

// dims: B=4 T=2048 M=2048 K=4096 D=1024 H=16 DH=64 FFN=4096

// ---------------- weight cast + transpose: Wt[n,k] = bf16(W[k,n]) ----------------
__global__ __launch_bounds__(256) void wt_cast_t(const float* __restrict__ W,
                                                 u16* __restrict__ Wt, int Kd, int Nd) {
  __shared__ float tile[32][33];
  const int n0 = blockIdx.x * 32, k0 = blockIdx.y * 32;
  const int t = threadIdx.x;
#pragma unroll
  for (int p = 0; p < 4; ++p) {
    int idx = p * 256 + t; int r = idx >> 5, c = idx & 31;
    tile[r][c] = W[(long)(k0 + r) * Nd + n0 + c];
  }
  __syncthreads();
#pragma unroll
  for (int p = 0; p < 4; ++p) {
    int idx = p * 256 + t; int r = idx >> 5, c = idx & 31;
    Wt[(long)(n0 + r) * Kd + k0 + c] = f2b(tile[c][r]);
  }
}

// ---------------- cb = bf16(concat(mem, x)) : [B,4096,1024] ----------------
__global__ __launch_bounds__(256) void build_cb(const float* __restrict__ x,
                                                const float* __restrict__ mem,
                                                u16* __restrict__ cb) {
  long idx = (long)blockIdx.x * 256 + threadIdx.x;  // one per 4 elems
  long e4 = idx * 4;
  int b = (int)(e4 >> 22);
  long rem = e4 & ((1L << 22) - 1);
  int tok = (int)(rem >> 10);
  int d = (int)(rem & 1023);
  const float* src = (tok < 2048) ? &mem[((long)b * 2048 + tok) * 1024 + d]
                                  : &x[((long)b * 2048 + (tok - 2048)) * 1024 + d];
  float4 vv = *(const float4*)src;
  uint2 o;
  o.x = (unsigned)f2b(vv.x) | ((unsigned)f2b(vv.y) << 16);
  o.y = (unsigned)f2b(vv.z) | ((unsigned)f2b(vv.w) << 16);
  *(uint2*)&cb[e4] = o;
}

// ---------------- pe[d, e] distance-indexed sinusoid table (bf16) ----------------
__global__ __launch_bounds__(256) void pos_emb(u16* __restrict__ pe) {
  const int d = blockIdx.x;          // 0..4095 (relative distance)
  const int e0 = threadIdx.x * 4;
  u16 o[4];
#pragma unroll
  for (int i = 0; i < 4; ++i) {
    int e = e0 + i;
    int f = (e < 512) ? e : (e - 512);
    float invf = expf(-(float)f * (9.210340371976184f / 512.f));  // 10000^(-f/512)
    float ang = (float)d * invf;
    o[i] = f2b((e < 512) ? sinf(ang) : cosf(ang));
  }
  uint2 pk; pk.x = (unsigned)o[0] | ((unsigned)o[1] << 16);
  pk.y = (unsigned)o[2] | ((unsigned)o[3] << 16);
  *(uint2*)&pe[(long)d * 1024 + e0] = pk;
}

#define EPI_BF16 0
#define EPI_F32 1
#define EPI_GELU 2
#define EPI_VT 3

// ---------------- small GEMM (r-proj): 128x128 tile, BK=64, proven r12 form ----
template <int EPI, int QMAP>
__global__ __launch_bounds__(256) void gemm_bt(const u16* __restrict__ A,
                                               const u16* __restrict__ Bt,
                                               const float* __restrict__ bias,
                                               void* __restrict__ outp, int Ndim, int Kdim) {
  __shared__ __align__(16) u16 As[128 * 64];
  __shared__ __align__(16) u16 Bs[128 * 64];
  const int col0 = blockIdx.x * 128;
  const int row0 = blockIdx.y * 128;
  const int t = threadIdx.x;
  const int w = t >> 6, l = t & 63;
  const int wr = (w >> 1) * 64, wc = (w & 1) * 64;
  const int lr = l & 15, g = l >> 4;
  f32x4 acc[4][4];
#pragma unroll
  for (int m = 0; m < 4; ++m)
#pragma unroll
    for (int n = 0; n < 4; ++n) acc[m][n] = f32x4{0.f, 0.f, 0.f, 0.f};

  for (int k0 = 0; k0 < Kdim; k0 += 64) {
#pragma unroll
    for (int it = 0; it < 4; ++it) {
      int c = it * 256 + t;
      int r = c >> 3, ch = (c & 7) ^ (r & 7);
      long ga = row0 + r;
      if (QMAP) ga = ((ga >> 11) << 12) + 2048 + (ga & 2047);
      GLD_LDS16(A + ga * Kdim + k0 + ch * 8, &As[c * 8]);
      GLD_LDS16(Bt + (long)(col0 + r) * Kdim + k0 + ch * 8, &Bs[c * 8]);
    }
    __syncthreads();
#pragma unroll
    for (int kk = 0; kk < 2; ++kk) {
      s16x8 af[4], bfv[4];
#pragma unroll
      for (int m = 0; m < 4; ++m) {
        int rm = wr + m * 16 + lr;
        af[m] = *(const s16x8*)&As[rm * 64 + (((g + 4 * kk) ^ (rm & 7)) << 3)];
      }
#pragma unroll
      for (int n = 0; n < 4; ++n) {
        int rn = wc + n * 16 + lr;
        bfv[n] = *(const s16x8*)&Bs[rn * 64 + (((g + 4 * kk) ^ (rn & 7)) << 3)];
      }
#pragma unroll
      for (int m = 0; m < 4; ++m)
#pragma unroll
        for (int n = 0; n < 4; ++n) acc[m][n] = MFMA16(af[m], bfv[n], acc[m][n]);
    }
    __syncthreads();
  }

  const int lg = g * 4;
#pragma unroll
  for (int m = 0; m < 4; ++m) {
    int rbase = row0 + wr + m * 16 + lg;
#pragma unroll
    for (int n = 0; n < 4; ++n) {
      int gc = col0 + wc + n * 16 + lr;
      float bv = bias ? bias[gc] : 0.f;
#pragma unroll
      for (int rg = 0; rg < 4; ++rg) {
        float vv = acc[m][n][rg] + bv;
        ((u16*)outp)[(long)(rbase + rg) * Ndim + gc] = f2b(vv);
      }
    }
  }
}

// ---------------- big GEMM: 256x128 tile, BK=64, TRIPLE-BUFFER + counted vmcnt ----
// True T4 (m218: counted-vs-drain0 = +38-73%): 3 LDS buffers; stages for tile
// t+2 issued during tile t, so at each tile boundary the buffer about to be
// read was staged a FULL TILE earlier (~800cy cover) and the wait retires only
// it: s_waitcnt vmcnt(6) + raw s_barrier (per-thread VMEM ops/tile = exactly
// 6 = 4 A + 2 B, uniform across waves — the precondition T4 needs; final tile
// waits 0). Soundness: each wave's vmcnt(6) retires ITS tile-t stages before
// the barrier, so after the barrier all waves' tile-t DMA writes are in LDS;
// the buffer being overwritten (t+2)%3 was last read in tile t-1 and those
// reads were consumed by MFMAs before that wave reached this barrier.
// No intra-tile barriers (r14's 8/tile were overhead without counted waits) —
// compiler schedules ds_read/MFMA with fine lgkmcnt. XOR swizzle = r12 scheme.
template <int EPI, int QMAP>
__global__ __launch_bounds__(512) void gemm_big(const u16* __restrict__ A,
                                                const u16* __restrict__ Bt,
                                                const float* __restrict__ bias,
                                                void* __restrict__ outp, int Ndim, int Kdim) {
  __shared__ __align__(16) u16 As[3][256 * 64];  // 96 KB
  __shared__ __align__(16) u16 Bs[3][128 * 64];  // 48 KB
  const int col0 = blockIdx.x * 128;
  const int row0 = blockIdx.y * 256;
  const int t = threadIdx.x;
  const int w = t >> 6, l = t & 63;
  const int wr = (w >> 2) * 128, wc = (w & 3) * 32;
  const int lr = l & 15, g = l >> 4;

  f32x4 acc[8][2];
#pragma unroll
  for (int m = 0; m < 8; ++m) {
    acc[m][0] = f32x4{0.f, 0.f, 0.f, 0.f};
    acc[m][1] = f32x4{0.f, 0.f, 0.f, 0.f};
  }

  // stage one K-tile into buffer nb: exactly 6 VMEM ops per thread (4 A + 2 B)
  auto STG = [&](int k0, int nb) {
#pragma unroll
    for (int p = 0; p < 4; ++p) {
      int c = p * 512 + t;
      int r = c >> 3, ch = (c & 7) ^ (r & 7);
      long ga = row0 + r;
      if (QMAP) ga = ((ga >> 11) << 12) + 2048 + (ga & 2047);
      GLD_LDS16(A + ga * Kdim + k0 + ch * 8, &As[nb][c * 8]);
    }
#pragma unroll
    for (int p = 0; p < 2; ++p) {
      int c = p * 512 + t;
      int r = c >> 3, ch = (c & 7) ^ (r & 7);
      GLD_LDS16(Bt + (long)(col0 + r) * Kdim + k0 + ch * 8, &Bs[nb][c * 8]);
    }
  };

  const int nt = Kdim >> 6;
  STG(0, 0);
  if (nt > 1) STG(64, 1);
  int cur = 0;

  for (int ti = 0; ti < nt; ++ti) {
    if (ti + 1 < nt) asm volatile("s_waitcnt vmcnt(6)\n\ts_barrier" ::: "memory");
    else             asm volatile("s_waitcnt vmcnt(0)\n\ts_barrier" ::: "memory");
    if (ti + 2 < nt) STG((ti + 2) << 6, (ti + 2) % 3);

    const u16* as = &As[cur][0];
    const u16* bs = &Bs[cur][0];
    s16x8 bf[2][2];
#pragma unroll
    for (int n = 0; n < 2; ++n) {
      int rn = wc + n * 16 + lr;
#pragma unroll
      for (int kk = 0; kk < 2; ++kk)
        bf[n][kk] = *(const s16x8*)&bs[rn * 64 + (((g + 4 * kk) ^ (rn & 7)) << 3)];
    }
    __builtin_amdgcn_s_setprio(1);
#pragma unroll
    for (int m = 0; m < 8; ++m) {
      int rm = wr + m * 16 + lr;
      s16x8 a0 = *(const s16x8*)&as[rm * 64 + ((g ^ (rm & 7)) << 3)];
      s16x8 a1 = *(const s16x8*)&as[rm * 64 + (((g + 4) ^ (rm & 7)) << 3)];
      acc[m][0] = MFMA16(a0, bf[0][0], acc[m][0]);
      acc[m][0] = MFMA16(a1, bf[0][1], acc[m][0]);
      acc[m][1] = MFMA16(a0, bf[1][0], acc[m][1]);
      acc[m][1] = MFMA16(a1, bf[1][1], acc[m][1]);
    }
    __builtin_amdgcn_s_setprio(0);
    cur = (cur == 2) ? 0 : cur + 1;
  }

  // ---- epilogue ----
  const int lg = g * 4;
#pragma unroll
  for (int m = 0; m < 8; ++m) {
    int rbase = row0 + wr + m * 16 + lg;
#pragma unroll
    for (int n = 0; n < 2; ++n) {
      int gc = col0 + wc + n * 16 + lr;
      float bv = bias ? bias[gc] : 0.f;
#pragma unroll
      for (int rg = 0; rg < 4; ++rg) {
        int grow = rbase + rg;
        float vv = acc[m][n][rg] + bv;
        if (EPI == EPI_GELU) {
          float x3 = vv * vv * vv;
          vv = 0.5f * vv * (1.f + tanhf(0.7978845608028654f * (vv + 0.044715f * x3)));
        }
        if (EPI == EPI_F32) {
          ((float*)outp)[(long)grow * Ndim + gc] = vv;
        } else if (EPI == EPI_VT) {
          int bb = grow >> 12, tok = grow & 4095;
          int hh = gc >> 6, dd = gc & 63;
          ((u16*)outp)[((long)((bb * 16 + hh) * 64 + dd) << 12) + tok] = f2b(vv);
        } else {
          ((u16*)outp)[(long)grow * Ndim + gc] = f2b(vv);
        }
      }
    }
  }
}

// ---------------- fused XL attention (r13, unchanged: 519us plateau) ----------------
#define SCALE_LOG2 0.18033688011111793f  // 0.125 * log2(e)

__global__ __launch_bounds__(1024, 4) void attn_fused(
    const u16* __restrict__ qg, const u16* __restrict__ kg, const u16* __restrict__ vTg,
    const u16* __restrict__ rg, const float* __restrict__ u, const float* __restrict__ vparam,
    const int* __restrict__ causal_p, u16* __restrict__ Og) {
  __shared__ __align__(16) u16 Ks[2][64 * 64];    // 16 KB
  __shared__ __align__(16) u16 Vs[2][64 * 64];    // 16 KB
  __shared__ __align__(16) u16 GPs[16][16 * 84];  // 42 KB per-wave G(84)/P(72) union

  const int bh = blockIdx.x, b = bh >> 4, h = bh & 15;
  const int i0 = (int)(gridDim.y - 1 - blockIdx.y) * 256;  // heavy tiles first
  const int t = threadIdx.x, w = t >> 6, l = t & 63;
  const int q = l & 15, g = l >> 4, lk = g * 8;
  const int causal = causal_p[0];

  const long kbase = ((long)b * 4096) * 1024 + h * 64;
  const long vbase = ((long)((b * 16 + h) * 64)) * 4096;

  const int irow = i0 + 16 * w + q;
  const u16* qp = qg + ((long)(b * 2048 + irow)) * 1024 + h * 64;
  s16x8 qlo = *(const s16x8*)(qp + lk);
  s16x8 qhi = *(const s16x8*)(qp + 32 + lk);
  s16x8 qu0, qu1, qv0, qv1;
#pragma unroll
  for (int j = 0; j < 8; ++j) {
    float a0 = b2f((u16)qlo[j]), a1 = b2f((u16)qhi[j]);
    float uu0 = u[h * 64 + lk + j], vv0 = vparam[h * 64 + lk + j];
    float uu1 = u[h * 64 + 32 + lk + j], vv1 = vparam[h * 64 + 32 + lk + j];
    qu0[j] = (short)f2b((a0 + uu0) * SCALE_LOG2); qv0[j] = (short)f2b((a0 + vv0) * SCALE_LOG2);
    qu1[j] = (short)f2b((a1 + uu1) * SCALE_LOG2); qv1[j] = (short)f2b((a1 + vv1) * SCALE_LOG2);
  }

  float lsum = 0.f;
  f32x4 oacc[4];
#pragma unroll
  for (int n = 0; n < 4; ++n) oacc[n] = f32x4{0.f, 0.f, 0.f, 0.f};

  u16* gpw = &GPs[w][0];
  const int kc0 = q * 64 + ((g ^ (q & 7)) << 3);
  const int kc1 = kc0 ^ 32;
  const int gq = q * 85 + 63;
  const int gst = q * 84 + 4 * g;
  const int pst = q * 72 + 4 * g;
  const int prd = q * 72 + lk;

  auto STAGE = [&](int j0s, int bufi) {
    int t9 = t & 511;
    int rrow = t9 >> 3, gch = (t9 & 7) ^ (rrow & 7);
    if (t < 512) GLD_LDS16(kg + kbase + (long)(j0s + rrow) * 1024 + gch * 8, &Ks[bufi][t9 * 8]);
    else         GLD_LDS16(vTg + vbase + (long)rrow * 4096 + j0s + gch * 8, &Vs[bufi][t9 * 8]);
  };

  s16x8 rf0[5], rf1[5];
  auto LOADR = [&](int j0r) {
    const int dlo = 2048 + i0 + 16 * w - j0r - 63;
#pragma unroll
    for (int tt = 0; tt < 5; ++tt) {
      int d = dlo + tt * 16 + q; d = min(max(d, 0), 4095);
      const u16* rp = rg + ((long)d << 10) + h * 64;
      rf0[tt] = *(const s16x8*)(rp + lk);
      rf1[tt] = *(const s16x8*)(rp + 32 + lk);
    }
  };

  const int jmax = causal ? (2048 + i0 + 256) : 4096;
  const int nt = jmax >> 6;
  const int jlimit = 2048 + i0 + 16 * w + 15;

  STAGE(0, 0);
  LOADR(0);
  int cur = 0;

  for (int ti = 0; ti < nt; ++ti) {
    const int j0 = ti << 6;
    __syncthreads();
    if (ti + 1 < nt) STAGE((ti + 1) << 6, cur ^ 1);

    if (!causal || j0 <= jlimit) {
      const u16* ksp = &Ks[cur][0];
      const u16* vsp = &Vs[cur][0];

      f32x4 sv[4];
      __builtin_amdgcn_s_setprio(1);
#pragma unroll
      for (int n = 0; n < 4; ++n) {
        s16x8 af0 = *(const s16x8*)&ksp[kc0 + n * 1024];
        s16x8 af1 = *(const s16x8*)&ksp[kc1 + n * 1024];
        f32x4 z = f32x4{0.f, 0.f, 0.f, 0.f};
        z = MFMA16(af0, qu0, z);
        z = MFMA16(af1, qu1, z);
        sv[n] = z;
      }
#pragma unroll
      for (int tt = 0; tt < 5; ++tt) {
        f32x4 z = f32x4{0.f, 0.f, 0.f, 0.f};
        z = MFMA16(rf0[tt], qv0, z);
        z = MFMA16(rf1[tt], qv1, z);
        uint2 gp2 = {pk_trunc(z[0], z[1]), pk_trunc(z[2], z[3])};
        *(u16x4*)&gpw[gst + tt * 16] = __builtin_bit_cast(u16x4, gp2);
      }
      __builtin_amdgcn_s_setprio(0);

      if (ti + 1 < nt && (!causal || j0 + 64 <= jlimit)) LOADR(j0 + 64);

      const bool need_mask = (causal != 0) && (j0 + 63 > 2048 + i0 + 16 * w);
#pragma unroll
      for (int n = 0; n < 4; ++n) {
#pragma unroll
        for (int r = 0; r < 4; ++r) {
          int j = 16 * n + 4 * g + r;
          float bd = b2f(gpw[gq - j]);
          float scv = sv[n][r] + bd;
          if (need_mask && (j0 + j > 2048 + irow)) scv = -3.0e38f;
          sv[n][r] = scv;
        }
      }
      float ls = 0.f;
#pragma unroll
      for (int n = 0; n < 4; ++n) {
        float p0 = __builtin_amdgcn_exp2f(sv[n][0]);
        float p1 = __builtin_amdgcn_exp2f(sv[n][1]);
        float p2 = __builtin_amdgcn_exp2f(sv[n][2]);
        float p3 = __builtin_amdgcn_exp2f(sv[n][3]);
        ls += (p0 + p1) + (p2 + p3);
        uint2 pp = {pk_trunc(p0, p1), pk_trunc(p2, p3)};
        *(u16x4*)&gpw[pst + n * 16] = __builtin_bit_cast(u16x4, pp);
      }
      lsum += ls;

      s16x8 pb0 = *(const s16x8*)&gpw[prd];
      s16x8 pb1 = *(const s16x8*)&gpw[prd + 32];
      __builtin_amdgcn_s_setprio(1);
#pragma unroll
      for (int n = 0; n < 4; ++n) {
        s16x8 va0 = *(const s16x8*)&vsp[kc0 + n * 1024];
        s16x8 va1 = *(const s16x8*)&vsp[kc1 + n * 1024];
        oacc[n] = MFMA16(va0, pb0, oacc[n]);
        oacc[n] = MFMA16(va1, pb1, oacc[n]);
      }
      __builtin_amdgcn_s_setprio(0);
    }
    cur ^= 1;
  }

  lsum += __shfl_xor(lsum, 16);
  lsum += __shfl_xor(lsum, 32);
  const float linv = 1.f / lsum;
  const long obase = (long)(b * 2048 + irow) * 1024 + h * 64;
#pragma unroll
  for (int n = 0; n < 4; ++n) {
    u16x4 ov = {f2b(oacc[n][0] * linv), f2b(oacc[n][1] * linv),
                f2b(oacc[n][2] * linv), f2b(oacc[n][3] * linv)};
    *(u16x4*)&Og[obase + n * 16 + 4 * g] = ov;
  }
}

// ---------------- LayerNorm(a + resid)*g + be -> fp32 (+optional bf16) ----------------
template <int WRITE_BF16>
__global__ __launch_bounds__(256) void ln_res(const float* __restrict__ a,
                                              const float* __restrict__ resid,
                                              const float* __restrict__ g,
                                              const float* __restrict__ be,
                                              float* __restrict__ outf, u16* __restrict__ outb) {
  const int row = blockIdx.x;
  const int t = threadIdx.x;
  const long base = (long)row * 1024;
  float4 av = *(const float4*)&a[base + t * 4];
  float4 rv = *(const float4*)&resid[base + t * 4];
  float x0 = av.x + rv.x, x1 = av.y + rv.y, x2 = av.z + rv.z, x3 = av.w + rv.w;
  float s = x0 + x1 + x2 + x3;
  float q = x0 * x0 + x1 * x1 + x2 * x2 + x3 * x3;
#pragma unroll
  for (int d = 1; d < 64; d <<= 1) {
    s += __shfl_xor(s, d);
    q += __shfl_xor(q, d);
  }
  __shared__ float ss[4], sq[4];
  if ((t & 63) == 0) { ss[t >> 6] = s; sq[t >> 6] = q; }
  __syncthreads();
  s = ss[0] + ss[1] + ss[2] + ss[3];
  q = sq[0] + sq[1] + sq[2] + sq[3];
  float mu = s * (1.f / 1024.f);
  float var = q * (1.f / 1024.f) - mu * mu;
  float rstd = rsqrtf(var + 1e-5f);
  float4 gv = *(const float4*)&g[t * 4];
  float4 bv = *(const float4*)&be[t * 4];
  float y0 = (x0 - mu) * rstd * gv.x + bv.x;
  float y1 = (x1 - mu) * rstd * gv.y + bv.y;
  float y2 = (x2 - mu) * rstd * gv.z + bv.z;
  float y3 = (x3 - mu) * rstd * gv.w + bv.w;
  float4 ov = {y0, y1, y2, y3};
  *(float4*)&outf[base + t * 4] = ov;
  if (WRITE_BF16) {
    uint2 o;
    o.x = (unsigned)f2b(y0) | ((unsigned)f2b(y1) << 16);
    o.y = (unsigned)f2b(y2) | ((unsigned)f2b(y3) << 16);
    *(uint2*)&outb[base + t * 4] = o;
  }
}

// ---------------- launcher ----------------
extern "C" void kernel_launch(void* const* d_in, const int* in_sizes, int n_in, void* d_out,
                              int out_size, void* d_ws, size_t ws_size, hipStream_t stream) {
  const float* x = (const float*)d_in[0];
  const float* mem = (const float*)d_in[1];
  const float* Wq = (const float*)d_in[2];
  const float* bq = (const float*)d_in[3];
  const float* Wk = (const float*)d_in[4];
  const float* bk = (const float*)d_in[5];
  const float* Wv = (const float*)d_in[6];
  const float* bv = (const float*)d_in[7];
  const float* Wo = (const float*)d_in[8];
  const float* bo = (const float*)d_in[9];
  const float* Wr = (const float*)d_in[10];
  const float* u = (const float*)d_in[11];
  const float* vp = (const float*)d_in[12];
  const float* g1 = (const float*)d_in[13];
  const float* be1 = (const float*)d_in[14];
  const float* g2 = (const float*)d_in[15];
  const float* be2 = (const float*)d_in[16];
  const float* W1 = (const float*)d_in[17];
  const float* b1 = (const float*)d_in[18];
  const float* W2 = (const float*)d_in[19];
  const float* b2 = (const float*)d_in[20];
  const int* iscaus = (const int*)d_in[21];

  char* ws = (char*)d_ws;
  const size_t MB = 1024 * 1024;
  u16* WqT = (u16*)(ws + 0 * MB);
  u16* WkT = (u16*)(ws + 2 * MB);
  u16* WvT = (u16*)(ws + 4 * MB);
  u16* WoT = (u16*)(ws + 6 * MB);
  u16* WrT = (u16*)(ws + 8 * MB);
  u16* W1T = (u16*)(ws + 10 * MB);
  u16* W2T = (u16*)(ws + 18 * MB);
  u16* cb = (u16*)(ws + 26 * MB);
  float* proj = (float*)(ws + 26 * MB);
  u16* pe = (u16*)(ws + 58 * MB);
  u16* qb = (u16*)(ws + 66 * MB);
  u16* kb = (u16*)(ws + 82 * MB);
  u16* vT = (u16*)(ws + 114 * MB);
  u16* rb = (u16*)(ws + 146 * MB);
  u16* aO = (u16*)(ws + 154 * MB);
  u16* hb = (u16*)(ws + 154 * MB);
  u16* f1 = (u16*)(ws + 58 * MB);
  float* f2 = (float*)(ws + 122 * MB);
  (void)ws_size; (void)in_sizes; (void)n_in; (void)out_size;

  wt_cast_t<<<dim3(32, 32), 256, 0, stream>>>(Wq, WqT, 1024, 1024);
  wt_cast_t<<<dim3(32, 32), 256, 0, stream>>>(Wk, WkT, 1024, 1024);
  wt_cast_t<<<dim3(32, 32), 256, 0, stream>>>(Wv, WvT, 1024, 1024);
  wt_cast_t<<<dim3(32, 32), 256, 0, stream>>>(Wo, WoT, 1024, 1024);
  wt_cast_t<<<dim3(32, 32), 256, 0, stream>>>(Wr, WrT, 1024, 1024);
  wt_cast_t<<<dim3(128, 32), 256, 0, stream>>>(W1, W1T, 1024, 4096);
  wt_cast_t<<<dim3(32, 128), 256, 0, stream>>>(W2, W2T, 4096, 1024);

  build_cb<<<16384, 256, 0, stream>>>(x, mem, cb);
  pos_emb<<<4096, 256, 0, stream>>>(pe);

  // projections (triple-buffer counted-vmcnt big GEMM, BN=128)
  gemm_big<EPI_BF16, 1><<<dim3(8, 32), 512, 0, stream>>>(cb, WqT, bq, qb, 1024, 1024);
  gemm_big<EPI_BF16, 0><<<dim3(8, 64), 512, 0, stream>>>(cb, WkT, bk, kb, 1024, 1024);
  gemm_big<EPI_VT, 0><<<dim3(8, 64), 512, 0, stream>>>(cb, WvT, bv, vT, 1024, 1024);
  gemm_bt<EPI_BF16, 0><<<dim3(8, 32), 256, 0, stream>>>(pe, WrT, nullptr, rb, 1024, 1024);

  // fused attention (r13)
  attn_fused<<<dim3(64, 8), 1024, 0, stream>>>(qb, kb, vT, rb, u, vp, iscaus, aO);

  // output projection + LN1
  gemm_big<EPI_F32, 0><<<dim3(8, 32), 512, 0, stream>>>(aO, WoT, bo, proj, 1024, 1024);
  ln_res<1><<<8192, 256, 0, stream>>>(proj, x, g1, be1, proj, hb);

  // FFN + LN2
  gemm_big<EPI_GELU, 0><<<dim3(32, 32), 512, 0, stream>>>(hb, W1T, b1, f1, 4096, 1024);
  gemm_big<EPI_F32, 0><<<dim3(8, 32), 512, 0, stream>>>(f1, W2T, b2, f2, 1024, 4096);
  ln_res<0><<<8192, 256, 0, stream>>>(f2, proj, g2, be2, (float*)d_out, nullptr);
}

// Round 16
// 907.763 us; speedup vs baseline: 1.0800x; 1.0800x over previous
//
#include <hip/hip_runtime.h>
#include <stdint.h>

// ---------------- common types / helpers ----------------
typedef unsigned short u16;
typedef short s16x8 __attribute__((ext_vector_type(8)));
typedef unsigned short u16x4 __attribute__((ext_vector_type(4)));
typedef float f32x4 __attribute__((ext_vector_type(4)));

#define DEV static __device__ __forceinline__

DEV u16 f2b(float f) {
  union { float f; unsigned u; } v; v.f = f;
  unsigned r = v.u + 0x7fffu + ((v.u >> 16) & 1u);
  return (u16)(r >> 16);
}
DEV float b2f(u16 b) {
  union { unsigned u; float f; } v; v.u = ((unsigned)b) << 16; return v.f;
}
// pack bf16(trunc(a)), bf16(trunc(b)) into one u32 with a single v_perm_b32
DEV unsigned pk_trunc(float a, float b) {
  return __builtin_amdgcn_perm(__float_as_uint(b), __float_as_uint(a), 0x07060302u);
}
DEV f32x4 MFMA16(s16x8 a, s16x8 b, f32x4 c) {
  return __builtin_amdgcn_mfma_f32_16x16x32_bf16(a, b, c, 0, 0, 0);
}
#define GLD_LDS16(gp, lp)                                                            \
  __builtin_amdgcn_global_load_lds((const __attribute__((address_space(1))) void*)(gp), \
                                   (__attribute__((address_space(3))) void*)(lp), 16, 0, 0)

// dims: B=4 T=2048 M=2048 K=4096 D=1024 H=16 DH=64 FFN=4096

// ---------------- weight cast + transpose: Wt[n,k] = bf16(W[k,n]) ----------------
__global__ __launch_bounds__(256) void wt_cast_t(const float* __restrict__ W,
                                                 u16* __restrict__ Wt, int Kd, int Nd) {
  __shared__ float tile[32][33];
  const int n0 = blockIdx.x * 32, k0 = blockIdx.y * 32;
  const int t = threadIdx.x;
#pragma unroll
  for (int p = 0; p < 4; ++p) {
    int idx = p * 256 + t; int r = idx >> 5, c = idx & 31;
    tile[r][c] = W[(long)(k0 + r) * Nd + n0 + c];
  }
  __syncthreads();
#pragma unroll
  for (int p = 0; p < 4; ++p) {
    int idx = p * 256 + t; int r = idx >> 5, c = idx & 31;
    Wt[(long)(n0 + r) * Kd + k0 + c] = f2b(tile[c][r]);
  }
}

// ---------------- cb = bf16(concat(mem, x)) : [B,4096,1024] ----------------
__global__ __launch_bounds__(256) void build_cb(const float* __restrict__ x,
                                                const float* __restrict__ mem,
                                                u16* __restrict__ cb) {
  long idx = (long)blockIdx.x * 256 + threadIdx.x;  // one per 4 elems
  long e4 = idx * 4;
  int b = (int)(e4 >> 22);
  long rem = e4 & ((1L << 22) - 1);
  int tok = (int)(rem >> 10);
  int d = (int)(rem & 1023);
  const float* src = (tok < 2048) ? &mem[((long)b * 2048 + tok) * 1024 + d]
                                  : &x[((long)b * 2048 + (tok - 2048)) * 1024 + d];
  float4 vv = *(const float4*)src;
  uint2 o;
  o.x = (unsigned)f2b(vv.x) | ((unsigned)f2b(vv.y) << 16);
  o.y = (unsigned)f2b(vv.z) | ((unsigned)f2b(vv.w) << 16);
  *(uint2*)&cb[e4] = o;
}

// ---------------- pe[d, e] distance-indexed sinusoid table (bf16) ----------------
__global__ __launch_bounds__(256) void pos_emb(u16* __restrict__ pe) {
  const int d = blockIdx.x;          // 0..4095 (relative distance)
  const int e0 = threadIdx.x * 4;
  u16 o[4];
#pragma unroll
  for (int i = 0; i < 4; ++i) {
    int e = e0 + i;
    int f = (e < 512) ? e : (e - 512);
    float invf = expf(-(float)f * (9.210340371976184f / 512.f));  // 10000^(-f/512)
    float ang = (float)d * invf;
    o[i] = f2b((e < 512) ? sinf(ang) : cosf(ang));
  }
  uint2 pk; pk.x = (unsigned)o[0] | ((unsigned)o[1] << 16);
  pk.y = (unsigned)o[2] | ((unsigned)o[3] << 16);
  *(uint2*)&pe[(long)d * 1024 + e0] = pk;
}

#define EPI_BF16 0
#define EPI_F32 1
#define EPI_GELU 2
#define EPI_VT 3

// ---------------- small GEMM (r-proj): 128x128 tile, BK=64, proven r12 form ----
template <int EPI, int QMAP>
__global__ __launch_bounds__(256) void gemm_bt(const u16* __restrict__ A,
                                               const u16* __restrict__ Bt,
                                               const float* __restrict__ bias,
                                               void* __restrict__ outp, int Ndim, int Kdim) {
  __shared__ __align__(16) u16 As[128 * 64];
  __shared__ __align__(16) u16 Bs[128 * 64];
  const int col0 = blockIdx.x * 128;
  const int row0 = blockIdx.y * 128;
  const int t = threadIdx.x;
  const int w = t >> 6, l = t & 63;
  const int wr = (w >> 1) * 64, wc = (w & 1) * 64;
  const int lr = l & 15, g = l >> 4;
  f32x4 acc[4][4];
#pragma unroll
  for (int m = 0; m < 4; ++m)
#pragma unroll
    for (int n = 0; n < 4; ++n) acc[m][n] = f32x4{0.f, 0.f, 0.f, 0.f};

  for (int k0 = 0; k0 < Kdim; k0 += 64) {
#pragma unroll
    for (int it = 0; it < 4; ++it) {
      int c = it * 256 + t;
      int r = c >> 3, ch = (c & 7) ^ (r & 7);
      long ga = row0 + r;
      if (QMAP) ga = ((ga >> 11) << 12) + 2048 + (ga & 2047);
      GLD_LDS16(A + ga * Kdim + k0 + ch * 8, &As[c * 8]);
      GLD_LDS16(Bt + (long)(col0 + r) * Kdim + k0 + ch * 8, &Bs[c * 8]);
    }
    __syncthreads();
#pragma unroll
    for (int kk = 0; kk < 2; ++kk) {
      s16x8 af[4], bfv[4];
#pragma unroll
      for (int m = 0; m < 4; ++m) {
        int rm = wr + m * 16 + lr;
        af[m] = *(const s16x8*)&As[rm * 64 + (((g + 4 * kk) ^ (rm & 7)) << 3)];
      }
#pragma unroll
      for (int n = 0; n < 4; ++n) {
        int rn = wc + n * 16 + lr;
        bfv[n] = *(const s16x8*)&Bs[rn * 64 + (((g + 4 * kk) ^ (rn & 7)) << 3)];
      }
#pragma unroll
      for (int m = 0; m < 4; ++m)
#pragma unroll
        for (int n = 0; n < 4; ++n) acc[m][n] = MFMA16(af[m], bfv[n], acc[m][n]);
    }
    __syncthreads();
  }

  const int lg = g * 4;
#pragma unroll
  for (int m = 0; m < 4; ++m) {
    int rbase = row0 + wr + m * 16 + lg;
#pragma unroll
    for (int n = 0; n < 4; ++n) {
      int gc = col0 + wc + n * 16 + lr;
      float bv = bias ? bias[gc] : 0.f;
#pragma unroll
      for (int rg = 0; rg < 4; ++rg) {
        float vv = acc[m][n][rg] + bv;
        ((u16*)outp)[(long)(rbase + rg) * Ndim + gc] = f2b(vv);
      }
    }
  }
}

// ---------------- big GEMM: 256xBN tile, BK=64, 8-wave 4-phase schedule (r14) ----
// Measured-best GEMM form (r14: non-attn 392us). Per K-tile 4 phases of
// {ds_read frag subtile (+all B frags in phase 0) | issue next-tile gld_lds
//  (front-loaded phases 0-2) | s_barrier | setprio MFMA cluster | s_barrier},
// then one __syncthreads per tile. (r15's triple-buffer counted-vmcnt variant
// REGRESSED: 1 monolithic MFMA cluster exposes the post-barrier ds_read burst;
// the 4-phase interleave is what pays, not the counted wait.)
template <int EPI, int QMAP, int BN>
__global__ __launch_bounds__(512) void gemm_big(const u16* __restrict__ A,
                                                const u16* __restrict__ Bt,
                                                const float* __restrict__ bias,
                                                void* __restrict__ outp, int Ndim, int Kdim) {
  constexpr int NF = BN / 64;  // B frags per wave (4 or 2)
  __shared__ __align__(16) u16 As[2][256 * 64];
  __shared__ __align__(16) u16 Bs[2][BN * 64];
  const int col0 = blockIdx.x * BN;
  const int row0 = blockIdx.y * 256;
  const int t = threadIdx.x;
  const int w = t >> 6, l = t & 63;
  const int wr = (w >> 2) * 128, wc = (w & 3) * (BN / 4);
  const int lr = l & 15, g = l >> 4;

  f32x4 acc[8][NF];
#pragma unroll
  for (int m = 0; m < 8; ++m)
#pragma unroll
    for (int n = 0; n < NF; ++n) acc[m][n] = f32x4{0.f, 0.f, 0.f, 0.f};

  auto stageA = [&](int k0, int p, int nb) {
    int c = p * 512 + t;
    int r = c >> 3, ch = (c & 7) ^ (r & 7);
    long ga = row0 + r;
    if (QMAP) ga = ((ga >> 11) << 12) + 2048 + (ga & 2047);
    GLD_LDS16(A + ga * Kdim + k0 + ch * 8, &As[nb][c * 8]);
  };
  auto stageB = [&](int k0, int p, int nb) {
    int c = p * 512 + t;
    int r = c >> 3, ch = (c & 7) ^ (r & 7);
    GLD_LDS16(Bt + (long)(col0 + r) * Kdim + k0 + ch * 8, &Bs[nb][c * 8]);
  };

  const int nt = Kdim >> 6;
#pragma unroll
  for (int p = 0; p < 4; ++p) stageA(0, p, 0);
#pragma unroll
  for (int p = 0; p < NF; ++p) stageB(0, p, 0);
  __syncthreads();
  int cur = 0;

  for (int ti = 0; ti < nt; ++ti) {
    const int k1 = (ti + 1) << 6;
    const int nb = cur ^ 1;
    s16x8 bf[NF][2];
#pragma unroll
    for (int p = 0; p < 4; ++p) {
      s16x8 af[2][2];
#pragma unroll
      for (int i = 0; i < 2; ++i) {
        int rm = wr + (2 * p + i) * 16 + lr;
#pragma unroll
        for (int kk = 0; kk < 2; ++kk)
          af[i][kk] = *(const s16x8*)&As[cur][rm * 64 + (((g + 4 * kk) ^ (rm & 7)) << 3)];
      }
      if (p == 0) {
#pragma unroll
        for (int n = 0; n < NF; ++n) {
          int rn = wc + n * 16 + lr;
#pragma unroll
          for (int kk = 0; kk < 2; ++kk)
            bf[n][kk] = *(const s16x8*)&Bs[cur][rn * 64 + (((g + 4 * kk) ^ (rn & 7)) << 3)];
        }
      }
      if (ti + 1 < nt) {
        if (p == 0) { stageA(k1, 0, nb); stageB(k1, 0, nb); }
        else if (p == 1) { stageA(k1, 1, nb); if (NF > 1) stageB(k1, 1, nb); }
        else if (p == 2) {
          stageA(k1, 2, nb); stageA(k1, 3, nb);
          if (NF == 4) { stageB(k1, 2, nb); stageB(k1, 3, nb); }
        }
      }
      __builtin_amdgcn_s_barrier();
      __builtin_amdgcn_s_setprio(1);
#pragma unroll
      for (int i = 0; i < 2; ++i)
#pragma unroll
        for (int n = 0; n < NF; ++n) {
          acc[2 * p + i][n] = MFMA16(af[i][0], bf[n][0], acc[2 * p + i][n]);
          acc[2 * p + i][n] = MFMA16(af[i][1], bf[n][1], acc[2 * p + i][n]);
        }
      __builtin_amdgcn_s_setprio(0);
      if (p < 3) __builtin_amdgcn_s_barrier();
    }
    __syncthreads();
    cur ^= 1;
  }

  // ---- epilogue ----
  const int lg = g * 4;
#pragma unroll
  for (int m = 0; m < 8; ++m) {
    int rbase = row0 + wr + m * 16 + lg;
#pragma unroll
    for (int n = 0; n < NF; ++n) {
      int gc = col0 + wc + n * 16 + lr;
      float bv = bias ? bias[gc] : 0.f;
#pragma unroll
      for (int rg = 0; rg < 4; ++rg) {
        int grow = rbase + rg;
        float vv = acc[m][n][rg] + bv;
        if (EPI == EPI_GELU) {
          float x3 = vv * vv * vv;
          vv = 0.5f * vv * (1.f + tanhf(0.7978845608028654f * (vv + 0.044715f * x3)));
        }
        if (EPI == EPI_F32) {
          ((float*)outp)[(long)grow * Ndim + gc] = vv;
        } else if (EPI == EPI_VT) {
          int bb = grow >> 12, tok = grow & 4095;
          int hh = gc >> 6, dd = gc & 63;
          ((u16*)outp)[((long)((bb * 16 + hh) * 64 + dd) << 12) + tok] = f2b(vv);
        } else {
          ((u16*)outp)[(long)grow * Ndim + gc] = f2b(vv);
        }
      }
    }
  }
}

// ---------------- fused XL attention, round-16: KVBLK=128 ----------------
// r13 body, but K/V staged 128 keys per barrier (two 64x64 subtiles per
// buffer; inner loop runs the unchanged 64-key body twice per staged tile).
// Halves __syncthreads + STAGE events per block — the per-tile lockstep
// overhead identified as the plateau mechanism. LDS 106.3KB -> 1 block/CU
// (16 waves ~= the 47% occupancy already measured at 75.8KB, so no loss).
// STAGE: each of 1024 threads stages ONE 16B K chunk + ONE 16B V chunk.
#define SCALE_LOG2 0.18033688011111793f  // 0.125 * log2(e)

__global__ __launch_bounds__(1024, 4) void attn_fused(
    const u16* __restrict__ qg, const u16* __restrict__ kg, const u16* __restrict__ vTg,
    const u16* __restrict__ rg, const float* __restrict__ u, const float* __restrict__ vparam,
    const int* __restrict__ causal_p, u16* __restrict__ Og) {
  __shared__ __align__(16) u16 Ks[2][128 * 64];   // 32 KB ([128 keys][64 dh], row-major)
  __shared__ __align__(16) u16 Vs[2][128 * 64];   // 32 KB (2 subtiles of [64 dh][64 keys])
  __shared__ __align__(16) u16 GPs[16][16 * 84];  // 42 KB per-wave G(84)/P(72) union

  const int bh = blockIdx.x, b = bh >> 4, h = bh & 15;
  const int i0 = (int)(gridDim.y - 1 - blockIdx.y) * 256;  // heavy tiles first
  const int t = threadIdx.x, w = t >> 6, l = t & 63;
  const int q = l & 15, g = l >> 4, lk = g * 8;
  const int causal = causal_p[0];

  const long kbase = ((long)b * 4096) * 1024 + h * 64;
  const long vbase = ((long)((b * 16 + h) * 64)) * 4096;

  const int irow = i0 + 16 * w + q;
  const u16* qp = qg + ((long)(b * 2048 + irow)) * 1024 + h * 64;
  s16x8 qlo = *(const s16x8*)(qp + lk);
  s16x8 qhi = *(const s16x8*)(qp + 32 + lk);
  s16x8 qu0, qu1, qv0, qv1;
#pragma unroll
  for (int j = 0; j < 8; ++j) {
    float a0 = b2f((u16)qlo[j]), a1 = b2f((u16)qhi[j]);
    float uu0 = u[h * 64 + lk + j], vv0 = vparam[h * 64 + lk + j];
    float uu1 = u[h * 64 + 32 + lk + j], vv1 = vparam[h * 64 + 32 + lk + j];
    qu0[j] = (short)f2b((a0 + uu0) * SCALE_LOG2); qv0[j] = (short)f2b((a0 + vv0) * SCALE_LOG2);
    qu1[j] = (short)f2b((a1 + uu1) * SCALE_LOG2); qv1[j] = (short)f2b((a1 + vv1) * SCALE_LOG2);
  }

  float lsum = 0.f;
  f32x4 oacc[4];
#pragma unroll
  for (int n = 0; n < 4; ++n) oacc[n] = f32x4{0.f, 0.f, 0.f, 0.f};

  u16* gpw = &GPs[w][0];
  const int kc0 = q * 64 + ((g ^ (q & 7)) << 3);
  const int kc1 = kc0 ^ 32;
  const int gq = q * 85 + 63;
  const int gst = q * 84 + 4 * g;
  const int pst = q * 72 + 4 * g;
  const int prd = q * 72 + lk;

  // stage 128-key K/V tile: thread t stages K chunk t ([128][64] row-major,
  // swizzled source) and V chunk t (two [64 dh][64 key] subtiles).
  auto STAGE = [&](int j0s, int bufi) {
    {
      int rrow = t >> 3, ch = (t & 7) ^ (rrow & 7);  // rrow 0..127
      GLD_LDS16(kg + kbase + (long)(j0s + rrow) * 1024 + ch * 8, &Ks[bufi][t * 8]);
    }
    {
      int s = t >> 9, c9 = t & 511;
      int rrow = c9 >> 3, ch = (c9 & 7) ^ (rrow & 7);  // rrow = dh 0..63
      GLD_LDS16(vTg + vbase + (long)rrow * 4096 + j0s + s * 64 + ch * 8,
                &Vs[bufi][(s << 12) + c9 * 8]);
    }
  };

  s16x8 rf0[5], rf1[5];
  auto LOADR = [&](int j0r) {
    const int dlo = 2048 + i0 + 16 * w - j0r - 63;
#pragma unroll
    for (int tt = 0; tt < 5; ++tt) {
      int d = dlo + tt * 16 + q; d = min(max(d, 0), 4095);
      const u16* rp = rg + ((long)d << 10) + h * 64;
      rf0[tt] = *(const s16x8*)(rp + lk);
      rf1[tt] = *(const s16x8*)(rp + 32 + lk);
    }
  };

  const int jmaxB = causal ? (2048 + i0 + 256) : 4096;  // multiple of 128
  const int NT = jmaxB >> 7;
  const int jlimit = 2048 + i0 + 16 * w + 15;  // last key any of this wave's rows needs

  STAGE(0, 0);
  LOADR(0);
  int cur = 0;

  for (int TI = 0; TI < NT; ++TI) {
    __syncthreads();
    if (TI + 1 < NT) STAGE((TI + 1) << 7, cur ^ 1);

#pragma unroll
    for (int s = 0; s < 2; ++s) {
      const int j0 = (TI << 7) + (s << 6);
      if (!causal || j0 <= jlimit) {
        const u16* ksp = &Ks[cur][s << 12];
        const u16* vsp = &Vs[cur][s << 12];

        f32x4 sv[4];
        __builtin_amdgcn_s_setprio(1);
#pragma unroll
        for (int n = 0; n < 4; ++n) {
          s16x8 af0 = *(const s16x8*)&ksp[kc0 + n * 1024];
          s16x8 af1 = *(const s16x8*)&ksp[kc1 + n * 1024];
          f32x4 z = f32x4{0.f, 0.f, 0.f, 0.f};
          z = MFMA16(af0, qu0, z);
          z = MFMA16(af1, qu1, z);
          sv[n] = z;
        }
#pragma unroll
        for (int tt = 0; tt < 5; ++tt) {
          f32x4 z = f32x4{0.f, 0.f, 0.f, 0.f};
          z = MFMA16(rf0[tt], qv0, z);
          z = MFMA16(rf1[tt], qv1, z);
          uint2 gp2 = {pk_trunc(z[0], z[1]), pk_trunc(z[2], z[3])};
          *(u16x4*)&gpw[gst + tt * 16] = __builtin_bit_cast(u16x4, gp2);
        }
        __builtin_amdgcn_s_setprio(0);

        // rf dead: prefetch R for the NEXT 64-subtile (hides under softmax+PV)
        if (j0 + 64 < jmaxB && (!causal || j0 + 64 <= jlimit)) LOADR(j0 + 64);

        const bool need_mask = (causal != 0) && (j0 + 63 > 2048 + i0 + 16 * w);
#pragma unroll
        for (int n = 0; n < 4; ++n) {
#pragma unroll
          for (int r = 0; r < 4; ++r) {
            int j = 16 * n + 4 * g + r;
            float bd = b2f(gpw[gq - j]);
            float scv = sv[n][r] + bd;
            if (need_mask && (j0 + j > 2048 + irow)) scv = -3.0e38f;
            sv[n][r] = scv;
          }
        }
        float ls = 0.f;
#pragma unroll
        for (int n = 0; n < 4; ++n) {
          float p0 = __builtin_amdgcn_exp2f(sv[n][0]);
          float p1 = __builtin_amdgcn_exp2f(sv[n][1]);
          float p2 = __builtin_amdgcn_exp2f(sv[n][2]);
          float p3 = __builtin_amdgcn_exp2f(sv[n][3]);
          ls += (p0 + p1) + (p2 + p3);
          uint2 pp = {pk_trunc(p0, p1), pk_trunc(p2, p3)};
          *(u16x4*)&gpw[pst + n * 16] = __builtin_bit_cast(u16x4, pp);
        }
        lsum += ls;

        s16x8 pb0 = *(const s16x8*)&gpw[prd];
        s16x8 pb1 = *(const s16x8*)&gpw[prd + 32];
        __builtin_amdgcn_s_setprio(1);
#pragma unroll
        for (int n = 0; n < 4; ++n) {
          s16x8 va0 = *(const s16x8*)&vsp[kc0 + n * 1024];
          s16x8 va1 = *(const s16x8*)&vsp[kc1 + n * 1024];
          oacc[n] = MFMA16(va0, pb0, oacc[n]);
          oacc[n] = MFMA16(va1, pb1, oacc[n]);
        }
        __builtin_amdgcn_s_setprio(0);
      }
    }
    cur ^= 1;
  }

  lsum += __shfl_xor(lsum, 16);
  lsum += __shfl_xor(lsum, 32);
  const float linv = 1.f / lsum;
  const long obase = (long)(b * 2048 + irow) * 1024 + h * 64;
#pragma unroll
  for (int n = 0; n < 4; ++n) {
    u16x4 ov = {f2b(oacc[n][0] * linv), f2b(oacc[n][1] * linv),
                f2b(oacc[n][2] * linv), f2b(oacc[n][3] * linv)};
    *(u16x4*)&Og[obase + n * 16 + 4 * g] = ov;
  }
}

// ---------------- LayerNorm(a + resid)*g + be -> fp32 (+optional bf16) ----------------
template <int WRITE_BF16>
__global__ __launch_bounds__(256) void ln_res(const float* __restrict__ a,
                                              const float* __restrict__ resid,
                                              const float* __restrict__ g,
                                              const float* __restrict__ be,
                                              float* __restrict__ outf, u16* __restrict__ outb) {
  const int row = blockIdx.x;
  const int t = threadIdx.x;
  const long base = (long)row * 1024;
  float4 av = *(const float4*)&a[base + t * 4];
  float4 rv = *(const float4*)&resid[base + t * 4];
  float x0 = av.x + rv.x, x1 = av.y + rv.y, x2 = av.z + rv.z, x3 = av.w + rv.w;
  float s = x0 + x1 + x2 + x3;
  float q = x0 * x0 + x1 * x1 + x2 * x2 + x3 * x3;
#pragma unroll
  for (int d = 1; d < 64; d <<= 1) {
    s += __shfl_xor(s, d);
    q += __shfl_xor(q, d);
  }
  __shared__ float ss[4], sq[4];
  if ((t & 63) == 0) { ss[t >> 6] = s; sq[t >> 6] = q; }
  __syncthreads();
  s = ss[0] + ss[1] + ss[2] + ss[3];
  q = sq[0] + sq[1] + sq[2] + sq[3];
  float mu = s * (1.f / 1024.f);
  float var = q * (1.f / 1024.f) - mu * mu;
  float rstd = rsqrtf(var + 1e-5f);
  float4 gv = *(const float4*)&g[t * 4];
  float4 bv = *(const float4*)&be[t * 4];
  float y0 = (x0 - mu) * rstd * gv.x + bv.x;
  float y1 = (x1 - mu) * rstd * gv.y + bv.y;
  float y2 = (x2 - mu) * rstd * gv.z + bv.z;
  float y3 = (x3 - mu) * rstd * gv.w + bv.w;
  float4 ov = {y0, y1, y2, y3};
  *(float4*)&outf[base + t * 4] = ov;
  if (WRITE_BF16) {
    uint2 o;
    o.x = (unsigned)f2b(y0) | ((unsigned)f2b(y1) << 16);
    o.y = (unsigned)f2b(y2) | ((unsigned)f2b(y3) << 16);
    *(uint2*)&outb[base + t * 4] = o;
  }
}

// ---------------- launcher ----------------
extern "C" void kernel_launch(void* const* d_in, const int* in_sizes, int n_in, void* d_out,
                              int out_size, void* d_ws, size_t ws_size, hipStream_t stream) {
  const float* x = (const float*)d_in[0];
  const float* mem = (const float*)d_in[1];
  const float* Wq = (const float*)d_in[2];
  const float* bq = (const float*)d_in[3];
  const float* Wk = (const float*)d_in[4];
  const float* bk = (const float*)d_in[5];
  const float* Wv = (const float*)d_in[6];
  const float* bv = (const float*)d_in[7];
  const float* Wo = (const float*)d_in[8];
  const float* bo = (const float*)d_in[9];
  const float* Wr = (const float*)d_in[10];
  const float* u = (const float*)d_in[11];
  const float* vp = (const float*)d_in[12];
  const float* g1 = (const float*)d_in[13];
  const float* be1 = (const float*)d_in[14];
  const float* g2 = (const float*)d_in[15];
  const float* be2 = (const float*)d_in[16];
  const float* W1 = (const float*)d_in[17];
  const float* b1 = (const float*)d_in[18];
  const float* W2 = (const float*)d_in[19];
  const float* b2 = (const float*)d_in[20];
  const int* iscaus = (const int*)d_in[21];

  char* ws = (char*)d_ws;
  const size_t MB = 1024 * 1024;
  u16* WqT = (u16*)(ws + 0 * MB);
  u16* WkT = (u16*)(ws + 2 * MB);
  u16* WvT = (u16*)(ws + 4 * MB);
  u16* WoT = (u16*)(ws + 6 * MB);
  u16* WrT = (u16*)(ws + 8 * MB);
  u16* W1T = (u16*)(ws + 10 * MB);
  u16* W2T = (u16*)(ws + 18 * MB);
  u16* cb = (u16*)(ws + 26 * MB);
  float* proj = (float*)(ws + 26 * MB);
  u16* pe = (u16*)(ws + 58 * MB);
  u16* qb = (u16*)(ws + 66 * MB);
  u16* kb = (u16*)(ws + 82 * MB);
  u16* vT = (u16*)(ws + 114 * MB);
  u16* rb = (u16*)(ws + 146 * MB);
  u16* aO = (u16*)(ws + 154 * MB);
  u16* hb = (u16*)(ws + 154 * MB);
  u16* f1 = (u16*)(ws + 58 * MB);
  float* f2 = (float*)(ws + 122 * MB);
  (void)ws_size; (void)in_sizes; (void)n_in; (void)out_size;

  wt_cast_t<<<dim3(32, 32), 256, 0, stream>>>(Wq, WqT, 1024, 1024);
  wt_cast_t<<<dim3(32, 32), 256, 0, stream>>>(Wk, WkT, 1024, 1024);
  wt_cast_t<<<dim3(32, 32), 256, 0, stream>>>(Wv, WvT, 1024, 1024);
  wt_cast_t<<<dim3(32, 32), 256, 0, stream>>>(Wo, WoT, 1024, 1024);
  wt_cast_t<<<dim3(32, 32), 256, 0, stream>>>(Wr, WrT, 1024, 1024);
  wt_cast_t<<<dim3(128, 32), 256, 0, stream>>>(W1, W1T, 1024, 4096);
  wt_cast_t<<<dim3(32, 128), 256, 0, stream>>>(W2, W2T, 4096, 1024);

  build_cb<<<16384, 256, 0, stream>>>(x, mem, cb);
  pos_emb<<<4096, 256, 0, stream>>>(pe);

  // projections (r14-measured 8-phase big GEMM mix)
  gemm_big<EPI_BF16, 1, 128><<<dim3(8, 32), 512, 0, stream>>>(cb, WqT, bq, qb, 1024, 1024);
  gemm_big<EPI_BF16, 0, 256><<<dim3(4, 64), 512, 0, stream>>>(cb, WkT, bk, kb, 1024, 1024);
  gemm_big<EPI_VT, 0, 256><<<dim3(4, 64), 512, 0, stream>>>(cb, WvT, bv, vT, 1024, 1024);
  gemm_bt<EPI_BF16, 0><<<dim3(8, 32), 256, 0, stream>>>(pe, WrT, nullptr, rb, 1024, 1024);

  // fused attention (KVBLK=128)
  attn_fused<<<dim3(64, 8), 1024, 0, stream>>>(qb, kb, vT, rb, u, vp, iscaus, aO);

  // output projection + LN1
  gemm_big<EPI_F32, 0, 128><<<dim3(8, 32), 512, 0, stream>>>(aO, WoT, bo, proj, 1024, 1024);
  ln_res<1><<<8192, 256, 0, stream>>>(proj, x, g1, be1, proj, hb);

  // FFN + LN2
  gemm_big<EPI_GELU, 0, 256><<<dim3(16, 32), 512, 0, stream>>>(hb, W1T, b1, f1, 4096, 1024);
  gemm_big<EPI_F32, 0, 128><<<dim3(8, 32), 512, 0, stream>>>(f1, W2T, b2, f2, 1024, 4096);
  ln_res<0><<<8192, 256, 0, stream>>>(f2, proj, g2, be2, (float*)d_out, nullptr);
}